// Round 1
// baseline (85.877 us; speedup 1.0000x reference)
//
#include <hip/hip_runtime.h>

// Problem constants
#define BATCH 2
#define NPTS 2048
#define NCH 64
#define IMG 128
#define KTOP 8
#define BIGF 1e10f
#define CAP 128   // per-row candidate capacity (expected ~48; CAP=128 verified R2-R5)

// ---------------------------------------------------------------------------
// Kernel 0: transpose src [B,C,P] -> srcT [B,P,C] in workspace.
// Makes one point's 64-channel feature vector contiguous (256 B), so the
// composite's per-point 16-channel gather is a single 64 B cache line
// (4x dwordx4) instead of 16 scalar loads at 8 KB stride.
// LDS-tiled 64x64, pad +1 (65 mod 32 == 1 -> conflict-free column reads).
// 64 blocks x 256 threads; ~2 MB of L2 traffic, ~1-2 us.
// ---------------------------------------------------------------------------
__global__ __launch_bounds__(256) void transpose_src(
    const float* __restrict__ src,   // [B, C, P]
    float* __restrict__ srcT) {      // [B, P, C]
  __shared__ float tile[64][65];
  const int blk = blockIdx.x;              // b*(P/64) + ptile
  const int b = blk >> 5;
  const int p0 = (blk & 31) << 6;
  const int lane = threadIdx.x & 63;
  const int wv = threadIdx.x >> 6;         // 0..3
  #pragma unroll
  for (int i = 0; i < 16; ++i) {
    const int c = (i << 2) + wv;
    tile[c][lane] = src[((size_t)b * NCH + c) * NPTS + p0 + lane];  // coalesced over p
  }
  __syncthreads();
  #pragma unroll
  for (int i = 0; i < 16; ++i) {
    const int r = (i << 2) + wv;
    srcT[((size_t)b * NPTS + p0 + r) * NCH + lane] = tile[lane][r]; // coalesced over c
  }
}

// ---------------------------------------------------------------------------
// Megakernel: scan + rasterize(top-8 z) + composite.
// Grid = B*IMG*2*4 = 4096 blocks x 64 threads (1 wave, 2 KB LDS -> high
// co-residency). Wave = (batch, row, half, 16-channel group); lane = pixel.
// Phases 1-2 unchanged from the verified 83.6 us version.
// Phase 3b now gathers from srcT [B,P,C] (64 B/point-group, float4 loads)
// and masks out empty top-k slots (wgt==0, ~7 of 8 on average) so inactive
// lanes issue no addresses.
// ---------------------------------------------------------------------------
__global__ __launch_bounds__(64) void raster_mega(
    const float* __restrict__ pts,   // [B, P, 3]
    const float* __restrict__ srcT,  // [B, P, C]  (transposed features)
    float* __restrict__ out) {       // [B, C, H, W]
  __shared__ float4 cand[CAP];       // (x, y, z, idx_bits), p-ordered

  const int bid = blockIdx.x;
  const int cg = bid & 3;            // 16-channel group
  const int half = (bid >> 2) & 1;
  const int h = (bid >> 3) & 127;
  const int b = bid >> 10;
  const int lane = threadIdx.x;

  const float r_ndc = 0.0234375f;    // RADIUS/SIZE*2 = 3/128, exact
  const float r2 = r_ndc * r_ndc;    // exact: 9*2^-14
  const float yc = 1.0f - 2.0f * (h + 0.5f) / 128.0f;

  // --- Phase 1: ballot-compacted scan into LDS (p-order preserved) ---
  const float* pb = pts + b * NPTS * 3;
  int base = 0;
  for (int it = 0; it < NPTS / 64; ++it) {   // 32 iterations
    int p = (it << 6) + lane;
    float y = pb[p * 3 + 1];                 // L1-hit (pts: 24 KB/batch)
    float dy = yc + y;                       // reference's dy, bit-exact
    bool hit = (dy * dy <= r2);
    unsigned long long mask = __ballot(hit);
    if (mask) {                              // wave-uniform branch
      if (hit) {
        int pos = base + __popcll(mask & ((1ull << lane) - 1ull));
        if (pos < CAP)
          cand[pos] = make_float4(pb[p * 3 + 0], y, pb[p * 3 + 2],
                                  __int_as_float(p));
      }
      base += __popcll(mask);
    }
  }
  __syncthreads();                           // 1 wave: just lgkmcnt drain
  const int cnt = min(base, CAP);

  const int w = (half << 6) + lane;
  const float xc = 1.0f - 2.0f * (w + 0.5f) / 128.0f;

  // --- Phase 2: top-8 by z asc; stable strict < == top_k order ---
  float bz[KTOP], bd[KTOP];
  int bp[KTOP];
  #pragma unroll
  for (int k = 0; k < KTOP; ++k) { bz[k] = BIGF; bd[k] = 0.f; bp[k] = 0; }

  for (int j = 0; j < cnt; ++j) {
    float4 c4 = cand[j];                     // LDS broadcast
    float dx = xc + c4.x;                    // == xc - (-x), reference's dx
    float dyy = yc + c4.y;
    float d2 = dx * dx + dyy * dyy;
    if (d2 <= r2) {                          // rare per lane (~0.9 hits avg)
      float cz = c4.z, cd = d2;
      int cp = __float_as_int(c4.w);
      #pragma unroll
      for (int s = 0; s < KTOP; ++s) {
        bool lt = (cz < bz[s]);              // strict: stability = tie-break
        float tz = bz[s], td = bd[s];
        int tp = bp[s];
        if (lt) { bz[s] = cz; bd[s] = cd; bp[s] = cp;
                  cz = tz; cd = td; cp = tp; }
      }
    }
  }

  // --- Phase 3a: weights ---
  float wgt[KTOP];
  float T = 1.0f;
  const float inv_r2 = 1.0f / r2;
  #pragma unroll
  for (int k = 0; k < KTOP; ++k) {
    float alpha = 0.0f;
    if (bz[k] < BIGF) {
      float dist = bd[k] * inv_r2;
      dist = fminf(fmaxf(dist, 0.001f), 1.0f);
      alpha = 1.0f - sqrtf(dist);
    }
    wgt[k] = alpha * T;                      // unfilled: bp=0 (safe), wgt=0
    T *= (1.0f - alpha);
  }

  // --- Phase 3b: composite 16 channels from srcT [B,P,C] ---
  // Each active (lane,k): one 64 B line = 4x float4. Empty slots (wgt==0,
  // ~7/8 avg) are exec-masked -> no address issued, no line touched.
  const float* st = srcT + (size_t)b * NPTS * NCH + cg * 16;
  float acc[16];
  #pragma unroll
  for (int c = 0; c < 16; ++c) acc[c] = 0.0f;
  #pragma unroll
  for (int k = 0; k < KTOP; ++k) {
    float wk = wgt[k];
    if (wk != 0.0f) {                        // contribution mathematically 0
      const float4* fp = (const float4*)(st + (size_t)bp[k] * NCH);
      float4 f0 = fp[0], f1 = fp[1], f2 = fp[2], f3 = fp[3];
      acc[0]  += wk * f0.x; acc[1]  += wk * f0.y;
      acc[2]  += wk * f0.z; acc[3]  += wk * f0.w;
      acc[4]  += wk * f1.x; acc[5]  += wk * f1.y;
      acc[6]  += wk * f1.z; acc[7]  += wk * f1.w;
      acc[8]  += wk * f2.x; acc[9]  += wk * f2.y;
      acc[10] += wk * f2.z; acc[11] += wk * f2.w;
      acc[12] += wk * f3.x; acc[13] += wk * f3.y;
      acc[14] += wk * f3.z; acc[15] += wk * f3.w;
    }
  }

  float* ob = out + (((size_t)b * NCH + cg * 16) * IMG + h) * IMG + w;
  const int S = IMG * IMG;
  #pragma unroll
  for (int c = 0; c < 16; ++c)
    ob[c * S] = acc[c];                      // coalesced over lanes (w)
}

extern "C" void kernel_launch(void* const* d_in, const int* in_sizes, int n_in,
                              void* d_out, int out_size, void* d_ws, size_t ws_size,
                              hipStream_t stream) {
  const float* pts = (const float*)d_in[0];   // [B,P,3]
  const float* src = (const float*)d_in[1];   // [B,C,P]
  float* out = (float*)d_out;                 // [B,C,H,W]
  float* srcT = (float*)d_ws;                 // [B,P,C] = 1 MB

  transpose_src<<<BATCH * (NPTS / 64), 256, 0, stream>>>(src, srcT);
  raster_mega<<<BATCH * IMG * 2 * 4, 64, 0, stream>>>(pts, srcT, out);
}

// Round 3
// 78.134 us; speedup vs baseline: 1.0991x; 1.0991x over previous
//
#include <hip/hip_runtime.h>

// Problem constants
#define BATCH 2
#define NPTS 2048
#define NCH 64
#define IMG 128
#define KTOP 8
#define BIGF 1e10f
#define SEGCAP 128   // per-segment candidate cap; = previously-verified full-row cap
#define NSEG 4

// ---------------------------------------------------------------------------
// Single megakernel: cooperative scan + rasterize(top-8 z) + composite.
// Grid = B*IMG*2 = 512 blocks x 256 threads (4 waves, 8 KB LDS).
// Block = (batch, row, half-row). Wave = 16-channel group; lane = pixel.
//
// Phase 1 (cooperative, segmented): wave w ballot-compacts points
//          [512w, 512w+512) into LDS segment w (8 iters vs 32 in the old
//          per-wave-scans-everything layout -> 4x less scan work and 4x
//          less global y-read traffic). dy^2 <= r2 is a conservative
//          superset of d2 <= r2; dy bit-identical to reference.
//          Segment-major iteration order == global p order, so the stable
//          strict-z insertion reproduces top_k's lowest-index tie-break.
// Phase 2: per-lane top-8 by z (stable insert), walking segments in order.
//          Redundant across the 4 waves (cheap: ~48 LDS-broadcast iters).
// Phase 3: alpha/transmittance weights; composite 16 channels per wave from
//          src [B,C,P] (L1/L2-resident scalar gathers, masked on wgt!=0);
//          coalesced stores over lanes (w).
// ---------------------------------------------------------------------------
__global__ __launch_bounds__(256) void raster_mega(
    const float* __restrict__ pts,   // [B, P, 3]
    const float* __restrict__ src,   // [B, C, P]
    float* __restrict__ out) {       // [B, C, H, W]
  __shared__ float4 cand[NSEG][SEGCAP];   // (x, y, z, idx_bits), p-ordered
  __shared__ int scnt[NSEG];

  const int bid = blockIdx.x;
  const int half = bid & 1;
  const int h = (bid >> 1) & (IMG - 1);
  const int b = bid >> 8;
  const int t = threadIdx.x;
  const int wv = t >> 6;             // wave id = scan segment = channel group
  const int lane = t & 63;

  const float r_ndc = 0.0234375f;    // RADIUS/SIZE*2 = 3/128, exact
  const float r2 = r_ndc * r_ndc;    // exact: 9*2^-14
  const float yc = 1.0f - 2.0f * (h + 0.5f) / 128.0f;

  // --- Phase 1: segmented ballot-compacted scan into LDS ---
  const float* pb = pts + b * NPTS * 3;
  int base = 0;
  for (int it = 0; it < NPTS / (64 * NSEG); ++it) {   // 8 iterations
    int p = (wv << 9) + (it << 6) + lane;
    float y = pb[p * 3 + 1];                 // L1-hit (pts: 24 KB/batch)
    float dy = yc + y;                       // reference's dy, bit-exact
    bool hit = (dy * dy <= r2);
    unsigned long long mask = __ballot(hit);
    if (mask) {                              // wave-uniform branch
      if (hit) {
        int pos = base + __popcll(mask & ((1ull << lane) - 1ull));
        if (pos < SEGCAP)
          cand[wv][pos] = make_float4(pb[p * 3 + 0], y, pb[p * 3 + 2],
                                      __int_as_float(p));
      }
      base += __popcll(mask);
    }
  }
  if (lane == 0) scnt[wv] = min(base, SEGCAP);
  __syncthreads();

  const int w = (half << 6) + lane;
  const float xc = 1.0f - 2.0f * (w + 0.5f) / 128.0f;

  // --- Phase 2: top-8 by z asc; stable strict < == top_k order ---
  float bz[KTOP], bd[KTOP];
  int bp[KTOP];
  #pragma unroll
  for (int k = 0; k < KTOP; ++k) { bz[k] = BIGF; bd[k] = 0.f; bp[k] = 0; }

  #pragma unroll 1
  for (int seg = 0; seg < NSEG; ++seg) {     // segments in p order
    const int cnt = scnt[seg];
    for (int j = 0; j < cnt; ++j) {
      float4 c4 = cand[seg][j];              // LDS broadcast
      float dx = xc + c4.x;                  // == xc - (-x), reference's dx
      float dyy = yc + c4.y;
      float d2 = dx * dx + dyy * dyy;
      if (d2 <= r2) {                        // rare per lane (~0.9 hits avg)
        float cz = c4.z, cd = d2;
        int cp = __float_as_int(c4.w);
        #pragma unroll
        for (int s = 0; s < KTOP; ++s) {
          bool lt = (cz < bz[s]);            // strict: stability = tie-break
          float tz = bz[s], td = bd[s];
          int tp = bp[s];
          if (lt) { bz[s] = cz; bd[s] = cd; bp[s] = cp;
                    cz = tz; cd = td; cp = tp; }
        }
      }
    }
  }

  // --- Phase 3a: weights ---
  float wgt[KTOP];
  float T = 1.0f;
  const float inv_r2 = 1.0f / r2;
  #pragma unroll
  for (int k = 0; k < KTOP; ++k) {
    float alpha = 0.0f;
    if (bz[k] < BIGF) {
      float dist = bd[k] * inv_r2;
      dist = fminf(fmaxf(dist, 0.001f), 1.0f);
      alpha = 1.0f - sqrtf(dist);
    }
    wgt[k] = alpha * T;                      // unfilled: bp=0 (safe), wgt=0
    T *= (1.0f - alpha);
  }

  // --- Phase 3b: composite 16 channels straight from src [B,C,P] ---
  const float* sb = src + ((size_t)b * NCH + wv * 16) * NPTS;
  float acc[16];
  #pragma unroll
  for (int c = 0; c < 16; ++c) acc[c] = 0.0f;
  #pragma unroll
  for (int k = 0; k < KTOP; ++k) {
    float wk = wgt[k];
    if (wk != 0.0f) {                        // empty slots issue no loads
      int p = bp[k];
      #pragma unroll
      for (int c = 0; c < 16; ++c)
        acc[c] += wk * sb[c * NPTS + p];     // L1/L2-hit scalar gathers
    }
  }

  float* ob = out + (((size_t)b * NCH + wv * 16) * IMG + h) * IMG + w;
  const int S = IMG * IMG;
  #pragma unroll
  for (int c = 0; c < 16; ++c)
    ob[c * S] = acc[c];                      // coalesced over lanes (w)
}

extern "C" void kernel_launch(void* const* d_in, const int* in_sizes, int n_in,
                              void* d_out, int out_size, void* d_ws, size_t ws_size,
                              hipStream_t stream) {
  const float* pts = (const float*)d_in[0];   // [B,P,3]
  const float* src = (const float*)d_in[1];   // [B,C,P]
  float* out = (float*)d_out;                 // [B,C,H,W]

  raster_mega<<<BATCH * IMG * 2, 256, 0, stream>>>(pts, src, out);
}